// Round 15
// baseline (477.444 us; speedup 1.0000x reference)
//
#include <hip/hip_runtime.h>

// LightweightConv1d: x (T,B,C) f32, weight (H,1,K) f32 (softmax over K), bias (C) f32
// out[t,b,c] = bias[c] + sum_k softmax(w[h])[k] * x[t-P+k, b, c],  h = c / (C/H)
//
// 128-bit loads/stores, compiler-scheduled (R14's asm crashed: async-load dest
// aliased a live input; "=v" is not early-clobber). Proven-safe pieces only:
// scalar-decomposed accumulators (structs spill: R8/R10), f32x4 loads (R10),
// nt dwordx4 stores (R12), per-lane weights (31 VGPR), boundary-only clamping.
// Duty model: 124 FMA (248 cyc) per f32x4 load vs ~600cyc latency -> 4-5 waves
// saturate VALU even load-serial; each load slot now moves 1024B (4x R6).
#define T_DIM 2048
#define B_DIM 32
#define C_DIM 512
#define H_DIM 16
#define K_DIM 31
#define P_PAD 15
#define TP 8                       // t-outputs per thread (x4 channels)
#define JN (TP + K_DIM - 1)        // 38 f32x4 rows per thread
#define NC4 (B_DIM * C_DIM / 4)    // 4096 float4 per t-row

typedef float f32x4 __attribute__((ext_vector_type(4)));

__global__ __launch_bounds__(256, 4)
void lwconv_kernel(const float* __restrict__ x, const float* __restrict__ weight,
                   const float* __restrict__ bias, float* __restrict__ out)
{
    const int tid  = threadIdx.x;
    const int w    = tid >> 6;                 // wave 0..3
    const int lane = tid & 63;
    const int bid  = blockIdx.x;
    const int tseg = bid & 63;                 // 32-t segment; 4 waves share halo
    const int co   = (bid >> 6) & 1;           // channel half
    const int b    = bid >> 7;                 // batch
    const int h    = (co << 3) | (lane >> 3);  // head, per-lane (8 heads/wave)
    const int col4 = b * (C_DIM / 4) + (co << 6) + lane;  // f32x4 col; wave = 1024B rows
    const int tb   = tseg * 32 + (w << 3);     // first output t of this thread

    // per-lane softmax of this lane's head weights (VGPR-resident)
    float wv[K_DIM];
    float m = -3.4e38f;
    #pragma unroll
    for (int k = 0; k < K_DIM; ++k) { wv[k] = weight[h * K_DIM + k]; m = fmaxf(m, wv[k]); }
    float s = 0.f;
    #pragma unroll
    for (int k = 0; k < K_DIM; ++k) { wv[k] = __expf(wv[k] - m); s += wv[k]; }
    const float inv = 1.f / s;
    #pragma unroll
    for (int k = 0; k < K_DIM; ++k) wv[k] *= inv;

    const f32x4 bv = ((const f32x4*)bias)[(co << 6) + lane];

    // scalar-decomposed accumulators: 4 arrays x 8 = 32 VGPRs, SROA-safe
    float aX[TP], aY[TP], aZ[TP], aW[TP];
    #pragma unroll
    for (int i = 0; i < TP; ++i) { aX[i] = bv[0]; aY[i] = bv[1]; aZ[i] = bv[2]; aW[i] = bv[3]; }

    const f32x4* xp4 = (const f32x4*)x + col4;

#define FMAROW(J, V)                                                      \
    {                                                                     \
        const int ilo = ((J) - (K_DIM - 1)) > 0 ? ((J) - (K_DIM - 1)) : 0;\
        const int ihi = (J) < (TP - 1) ? (J) : (TP - 1);                  \
        _Pragma("unroll")                                                 \
        for (int i = ilo; i <= ihi; ++i) {                                \
            const float wk = wv[(J) - i];                                 \
            aX[i] = fmaf(wk, (V)[0], aX[i]);                              \
            aY[i] = fmaf(wk, (V)[1], aY[i]);                              \
            aZ[i] = fmaf(wk, (V)[2], aZ[i]);                              \
            aW[i] = fmaf(wk, (V)[3], aW[i]);                              \
        }                                                                 \
    }

    if (tseg == 0 || tseg == 63) {
        // boundary segments (2/64 of blocks): clamp + zero out-of-range rows
        #pragma unroll
        for (int j = 0; j < JN; ++j) {
            const int t = tb - P_PAD + j;
            int tc = t < 0 ? 0 : (t >= T_DIM ? T_DIM - 1 : t);
            f32x4 v = xp4[(size_t)tc * NC4];
            if (t < 0 || t >= T_DIM) { v[0] = 0.f; v[1] = 0.f; v[2] = 0.f; v[3] = 0.f; }
            FMAROW(j, v);
        }
    } else {
        // interior: rows tb-15 .. tb+22 all in-range; branch-free stream
        #pragma unroll
        for (int j = 0; j < JN; ++j) {
            f32x4 v = xp4[(size_t)(tb - P_PAD + j) * NC4];
            FMAROW(j, v);
        }
    }
#undef FMAROW

    // nt dwordx4 stores (1024B/wave/instr); keep output out of L3 (R12)
    f32x4* op4 = (f32x4*)out + col4;
    #pragma unroll
    for (int i = 0; i < TP; ++i) {
        f32x4 r; r[0] = aX[i]; r[1] = aY[i]; r[2] = aZ[i]; r[3] = aW[i];
        __builtin_nontemporal_store(r, &op4[(size_t)(tb + i) * NC4]);
    }
}

extern "C" void kernel_launch(void* const* d_in, const int* in_sizes, int n_in,
                              void* d_out, int out_size, void* d_ws, size_t ws_size,
                              hipStream_t stream) {
    const float* x      = (const float*)d_in[0];
    const float* weight = (const float*)d_in[1];
    const float* bias   = (const float*)d_in[2];
    float* out = (float*)d_out;
    // blocks: tseg(64) x co(2) x b(32) = 4096, each 4 waves sharing a 32-t halo
    dim3 grid(64 * 2 * B_DIM);
    dim3 block(256);
    lwconv_kernel<<<grid, block, 0, stream>>>(x, weight, bias, out);
}

// Round 16
// 298.224 us; speedup vs baseline: 1.6010x; 1.6010x over previous
//
#include <hip/hip_runtime.h>

// LightweightConv1d: x (T,B,C) f32, weight (H,1,K) f32 (softmax over K), bias (C) f32
// out[t,b,c] = bias[c] + sum_k softmax(w[h])[k] * x[t-P+k, b, c],  h = c / (C/H)
//
// R13's asm-pipelined skeleton (the ONLY proven scheduler/allocator control:
// VGPR=48, no spill, counted vmcnt) widened to dwordx4. R14's crash root-cause:
// "=v" allowed load-dest == voff; voff increment + async return => wild addrs.
// Fixed with "=&v" early-clobber. R15's lesson: compiler-scheduled wide loads
// hoist & spill -- so ALL interior loads are asm-opaque. Unified path: clamped
// wave-uniform row addresses + branch-free zero-multiplier (no boundary branch,
// no compiler loads, no hoist risk). Thread = 4ch x 8t; wave = 1 head x 8
// batches (weights in SGPR); 2-deep batches of 4 loads (8KB/wave in flight).
#define T_DIM 2048
#define B_DIM 32
#define C_DIM 512
#define H_DIM 16
#define K_DIM 31
#define P_PAD 15
#define TP 8                       // t-outputs per thread (x4 channels)
#define JN (TP + K_DIM - 1)        // 38 f32x4 rows per thread
#define NC4 (B_DIM * C_DIM / 4)    // 4096 float4 per t-row

typedef float f32x4 __attribute__((ext_vector_type(4)));

__global__ __launch_bounds__(256, 4)
void lwconv_kernel(const float* __restrict__ x, const float* __restrict__ weight,
                   const float* __restrict__ bias, float* __restrict__ out)
{
    const int wid  = __builtin_amdgcn_readfirstlane((int)(threadIdx.x >> 6));
    const int lane = threadIdx.x & 63;
    const int gw   = blockIdx.x * 4 + wid;       // global wave id (scalar)
    const int h    = gw & (H_DIM - 1);           // head (wave-uniform)
    const int bo   = (gw >> 4) & 3;              // batch octet (uniform)
    const int tblk = gw >> 6;                    // t-block 0..255 (uniform)
    const int c4   = lane & 7;                   // f32x4-col within head (8 = 32ch)
    const int b    = (bo << 3) | (lane >> 3);    // 8 batches per wave
    const int col4 = b * (C_DIM / 4) + (h << 3) + c4;  // f32x4 index in a t-row
    const int tb   = tblk * TP;                  // first output t (uniform)

    // per-lane softmax of the head's 31 weights (uniform inputs), then -> SGPR
    float w[K_DIM];
    float m = -3.4e38f;
    #pragma unroll
    for (int k = 0; k < K_DIM; ++k) { w[k] = weight[h * K_DIM + k]; m = fmaxf(m, w[k]); }
    float s = 0.f;
    #pragma unroll
    for (int k = 0; k < K_DIM; ++k) { w[k] = __expf(w[k] - m); s += w[k]; }
    const float inv = 1.f / s;
    unsigned int ws[K_DIM];
    #pragma unroll
    for (int k = 0; k < K_DIM; ++k)
        ws[k] = __builtin_amdgcn_readfirstlane(__float_as_uint(w[k] * inv));

    const f32x4 bv = ((const f32x4*)bias)[(h << 3) + c4];

    // scalar-decomposed accumulators: 4 arrays x 8 = 32 VGPRs, SROA-safe
    float aX[TP], aY[TP], aZ[TP], aW[TP];
    #pragma unroll
    for (int i = 0; i < TP; ++i) { aX[i] = bv[0]; aY[i] = bv[1]; aZ[i] = bv[2]; aW[i] = bv[3]; }

    const unsigned long long xb = (unsigned long long)(const void*)x;
    const unsigned vbase = (unsigned)col4 << 4;  // byte offset of the column
    f32x4 A0, A1, A2, A3, B0, B1, B2, B3, T0, T1;

    // Issue row J: clamped wave-uniform t -> SGPR offset; one v_add per row.
    // "=&v": early-clobber -- dest may not alias voff/base (R14 fix).
#define ISSUE(BUF, J)                                                     \
    {                                                                     \
        const int t_ = tb - P_PAD + (J);                                  \
        const int tc_ = t_ < 0 ? 0 : (t_ > T_DIM - 1 ? T_DIM - 1 : t_);  \
        const unsigned voff_ = vbase + ((unsigned)tc_ << 16);             \
        asm volatile("global_load_dwordx4 %0, %1, %2"                     \
                     : "=&v"(BUF) : "v"(voff_), "s"(xb));                 \
    }

#define WAIT4(N, P0, P1, P2, P3)                                          \
    asm volatile("s_waitcnt vmcnt(" #N ")"                                \
                 : "+v"(P0), "+v"(P1), "+v"(P2), "+v"(P3));

#define WAIT2(N, P0, P1)                                                  \
    asm volatile("s_waitcnt vmcnt(" #N ")" : "+v"(P0), "+v"(P1));

    // Branch-free edge zeroing: multiply by uniform 0/1 (only first/last tblk
    // ever have invalid rows; costs 4 v_mul per row everywhere).
#define FIX(J, V)                                                         \
    {                                                                     \
        const int t_ = tb - P_PAD + (J);                                  \
        const float zf_ = (t_ >= 0 && t_ < T_DIM) ? 1.f : 0.f;            \
        (V)[0] *= zf_; (V)[1] *= zf_; (V)[2] *= zf_; (V)[3] *= zf_;       \
    }

#define FMAROW(J, V)                                                      \
    {                                                                     \
        const int ilo = ((J) - (K_DIM - 1)) > 0 ? ((J) - (K_DIM - 1)) : 0;\
        const int ihi = (J) < (TP - 1) ? (J) : (TP - 1);                  \
        _Pragma("unroll")                                                 \
        for (int i = ilo; i <= ihi; ++i) {                                \
            const float wk = __uint_as_float(ws[(J) - i]);                \
            aX[i] = fmaf(wk, (V)[0], aX[i]);                              \
            aY[i] = fmaf(wk, (V)[1], aY[i]);                              \
            aZ[i] = fmaf(wk, (V)[2], aZ[i]);                              \
            aW[i] = fmaf(wk, (V)[3], aW[i]);                              \
        }                                                                 \
    }

#define STEP4(BASE, P0, P1, P2, P3)                                       \
    FIX((BASE) + 0, P0) FMAROW((BASE) + 0, P0)                            \
    FIX((BASE) + 1, P1) FMAROW((BASE) + 1, P1)                            \
    FIX((BASE) + 2, P2) FMAROW((BASE) + 2, P2)                            \
    FIX((BASE) + 3, P3) FMAROW((BASE) + 3, P3)

    ISSUE(A0, 0)  ISSUE(A1, 1)  ISSUE(A2, 2)  ISSUE(A3, 3)    // 4 in flight
    ISSUE(B0, 4)  ISSUE(B1, 5)  ISSUE(B2, 6)  ISSUE(B3, 7)    // 8 in flight
    WAIT4(4, A0, A1, A2, A3) STEP4(0,  A0, A1, A2, A3)
    ISSUE(A0, 8)  ISSUE(A1, 9)  ISSUE(A2, 10) ISSUE(A3, 11)
    WAIT4(4, B0, B1, B2, B3) STEP4(4,  B0, B1, B2, B3)
    ISSUE(B0, 12) ISSUE(B1, 13) ISSUE(B2, 14) ISSUE(B3, 15)
    WAIT4(4, A0, A1, A2, A3) STEP4(8,  A0, A1, A2, A3)
    ISSUE(A0, 16) ISSUE(A1, 17) ISSUE(A2, 18) ISSUE(A3, 19)
    WAIT4(4, B0, B1, B2, B3) STEP4(12, B0, B1, B2, B3)
    ISSUE(B0, 20) ISSUE(B1, 21) ISSUE(B2, 22) ISSUE(B3, 23)
    WAIT4(4, A0, A1, A2, A3) STEP4(16, A0, A1, A2, A3)
    ISSUE(A0, 24) ISSUE(A1, 25) ISSUE(A2, 26) ISSUE(A3, 27)
    WAIT4(4, B0, B1, B2, B3) STEP4(20, B0, B1, B2, B3)
    ISSUE(B0, 28) ISSUE(B1, 29) ISSUE(B2, 30) ISSUE(B3, 31)
    WAIT4(4, A0, A1, A2, A3) STEP4(24, A0, A1, A2, A3)
    ISSUE(A0, 32) ISSUE(A1, 33) ISSUE(A2, 34) ISSUE(A3, 35)
    WAIT4(4, B0, B1, B2, B3) STEP4(28, B0, B1, B2, B3)
    ISSUE(T0, 36) ISSUE(T1, 37)                               // 6 in flight
    WAIT4(2, A0, A1, A2, A3) STEP4(32, A0, A1, A2, A3)
    WAIT2(0, T0, T1)
    FIX(36, T0) FMAROW(36, T0)
    FIX(37, T1) FMAROW(37, T1)

#undef ISSUE
#undef WAIT4
#undef WAIT2
#undef FIX
#undef FMAROW
#undef STEP4

    // nt dwordx4 stores (1024B/wave/instr); keep output out of L3 (R12)
    f32x4* op4 = (f32x4*)out + col4;
    #pragma unroll
    for (int i = 0; i < TP; ++i) {
        f32x4 r; r[0] = aX[i]; r[1] = aY[i]; r[2] = aZ[i]; r[3] = aW[i];
        __builtin_nontemporal_store(r, &op4[(size_t)(tb + i) * NC4]);
    }
}

extern "C" void kernel_launch(void* const* d_in, const int* in_sizes, int n_in,
                              void* d_out, int out_size, void* d_ws, size_t ws_size,
                              hipStream_t stream) {
    const float* x      = (const float*)d_in[0];
    const float* weight = (const float*)d_in[1];
    const float* bias   = (const float*)d_in[2];
    float* out = (float*)d_out;
    // waves = heads(16) x batch-octets(4) x t-blocks(256) = 16384 -> 4096 blocks
    dim3 grid(H_DIM * 4 * (T_DIM / TP) / 4);
    dim3 block(256);
    lwconv_kernel<<<grid, block, 0, stream>>>(x, weight, bias, out);
}

// Round 18
// 56.158 us; speedup vs baseline: 8.5018x; 5.3105x over previous
//
#include <hip/hip_runtime.h>

// LightweightConv1d: x (T,B,C) f32, weight (H,1,K) f32 (softmax over K), bias (C) f32
// out[t,b,c] = bias[c] + sum_k softmax(w[h])[k] * x[t-P+k, b, c],  h = c / (C/H)
//
// R13's proven asm-pipeline skeleton widened to dwordx2 (512B/wave-request).
// Width-hypothesis test: all dword kernels pin at ~4.05 TB/s; m13's 1024B-req
// copy hits 6.29. Allocator-safety rules (learned R5/R8/R10/R15/R16/R17):
//   - scalar accumulator arrays only (structs spill wholesale)
//   - asm-opaque loads, "=&v" early-clobber (R14 crash fix)
//   - NO waves_per_eu pin (R17: forced ceiling -> spill of pending-load dest
//     -> silent corruption); launch_bounds(256,4) like R13 (correct, VGPR=48)
//   - counted vmcnt, never 0 until drain; boundary via same ladder + zero-mult
#define T_DIM 2048
#define B_DIM 32
#define C_DIM 512
#define H_DIM 16
#define K_DIM 31
#define P_PAD 15
#define TP 16                      // t-outputs per thread (x2 channels)
#define NC2 (B_DIM * C_DIM / 2)    // 8192 f32x2 per t-row

typedef float f32x2 __attribute__((ext_vector_type(2)));

__global__ __launch_bounds__(256, 4)
void lwconv_kernel(const float* __restrict__ x, const float* __restrict__ weight,
                   const float* __restrict__ bias, float* __restrict__ out)
{
    const int wid  = __builtin_amdgcn_readfirstlane((int)(threadIdx.x >> 6));
    const int lane = threadIdx.x & 63;
    const int gw   = blockIdx.x * 4 + wid;       // global wave id (scalar)
    const int h    = gw & (H_DIM - 1);           // head (wave-uniform)
    const int bq   = (gw >> 4) & 7;              // batch quad (uniform)
    const int tblk = gw >> 7;                    // t-block 0..127 (uniform)
    const int c2   = lane & 15;                  // f32x2-col within head (16 = 32ch)
    const int b    = (bq << 2) | (lane >> 4);    // 4 batches per wave
    const int col2 = b * (C_DIM / 2) + (h << 4) + c2;  // f32x2 index in a t-row
    const int tb   = tblk * TP;                  // first output t (uniform)

    // per-lane softmax of the head's 31 weights (uniform inputs), then -> SGPR
    float w[K_DIM];
    float m = -3.4e38f;
    #pragma unroll
    for (int k = 0; k < K_DIM; ++k) { w[k] = weight[h * K_DIM + k]; m = fmaxf(m, w[k]); }
    float s = 0.f;
    #pragma unroll
    for (int k = 0; k < K_DIM; ++k) { w[k] = __expf(w[k] - m); s += w[k]; }
    const float inv = 1.f / s;
    unsigned int ws[K_DIM];
    #pragma unroll
    for (int k = 0; k < K_DIM; ++k)
        ws[k] = __builtin_amdgcn_readfirstlane(__float_as_uint(w[k] * inv));

    const f32x2 bv = ((const f32x2*)bias)[(h << 4) + c2];

    // scalar-decomposed accumulators: 2 arrays x 16 = 32 VGPRs (SROA-proven)
    float aA[TP], aB[TP];
    #pragma unroll
    for (int i = 0; i < TP; ++i) { aA[i] = bv[0]; aB[i] = bv[1]; }

    const unsigned long long xb = (unsigned long long)(const void*)x;
    const unsigned vbase = (unsigned)col2 << 3;  // byte offset of the column
    f32x2 A0, A1, A2, A3, A4, A5, A6, A7;        // batch A (16 VGPR)
    f32x2 B0, B1, B2, B3, B4, B5, B6, B7;        // batch B (16 VGPR)

    // clamped wave-uniform row address; "=&v" early-clobber (R14 fix)
#define ISSUE(BUF, J)                                                     \
    {                                                                     \
        const int t_ = tb - P_PAD + (J);                                  \
        const int tc_ = t_ < 0 ? 0 : (t_ > T_DIM - 1 ? T_DIM - 1 : t_);   \
        const unsigned voff_ = vbase + ((unsigned)tc_ << 16);             \
        asm volatile("global_load_dwordx2 %0, %1, %2"                     \
                     : "=&v"(BUF) : "v"(voff_), "s"(xb));                 \
    }

#define WAIT8(N, P0, P1, P2, P3, P4, P5, P6, P7)                          \
    asm volatile("s_waitcnt vmcnt(" #N ")"                                \
                 : "+v"(P0), "+v"(P1), "+v"(P2), "+v"(P3),                \
                   "+v"(P4), "+v"(P5), "+v"(P6), "+v"(P7));

#define WAIT6(N, P0, P1, P2, P3, P4, P5)                                  \
    asm volatile("s_waitcnt vmcnt(" #N ")"                                \
                 : "+v"(P0), "+v"(P1), "+v"(P2), "+v"(P3),                \
                   "+v"(P4), "+v"(P5));

#define FMAROW(J, V)                                                      \
    {                                                                     \
        const int ilo = ((J) - (K_DIM - 1)) > 0 ? ((J) - (K_DIM - 1)) : 0;\
        const int ihi = (J) < (TP - 1) ? (J) : (TP - 1);                  \
        _Pragma("unroll")                                                 \
        for (int i = ilo; i <= ihi; ++i) {                                \
            const float wk = __uint_as_float(ws[(J) - i]);                \
            aA[i] = fmaf(wk, (V)[0], aA[i]);                              \
            aB[i] = fmaf(wk, (V)[1], aB[i]);                              \
        }                                                                 \
    }

    // zero-mult edge fix (boundary ladder only)
#define FIX(J, V)                                                         \
    {                                                                     \
        const int t_ = tb - P_PAD + (J);                                  \
        const float zf_ = (t_ >= 0 && t_ < T_DIM) ? 1.f : 0.f;            \
        (V)[0] *= zf_; (V)[1] *= zf_;                                     \
    }

    // 46 rows: batches 8,8,8,8,8,6; 2-deep (16 loads / 8KB-equivalent in flight)
#define LADDER(R)                                                          \
    ISSUE(A0,0) ISSUE(A1,1) ISSUE(A2,2) ISSUE(A3,3)                        \
    ISSUE(A4,4) ISSUE(A5,5) ISSUE(A6,6) ISSUE(A7,7)                        \
    ISSUE(B0,8) ISSUE(B1,9) ISSUE(B2,10) ISSUE(B3,11)                      \
    ISSUE(B4,12) ISSUE(B5,13) ISSUE(B6,14) ISSUE(B7,15)                    \
    WAIT8(8, A0,A1,A2,A3,A4,A5,A6,A7)                                      \
    R(0,A0) R(1,A1) R(2,A2) R(3,A3) R(4,A4) R(5,A5) R(6,A6) R(7,A7)        \
    ISSUE(A0,16) ISSUE(A1,17) ISSUE(A2,18) ISSUE(A3,19)                    \
    ISSUE(A4,20) ISSUE(A5,21) ISSUE(A6,22) ISSUE(A7,23)                    \
    WAIT8(8, B0,B1,B2,B3,B4,B5,B6,B7)                                      \
    R(8,B0) R(9,B1) R(10,B2) R(11,B3) R(12,B4) R(13,B5) R(14,B6) R(15,B7)  \
    ISSUE(B0,24) ISSUE(B1,25) ISSUE(B2,26) ISSUE(B3,27)                    \
    ISSUE(B4,28) ISSUE(B5,29) ISSUE(B6,30) ISSUE(B7,31)                    \
    WAIT8(8, A0,A1,A2,A3,A4,A5,A6,A7)                                      \
    R(16,A0) R(17,A1) R(18,A2) R(19,A3) R(20,A4) R(21,A5) R(22,A6) R(23,A7)\
    ISSUE(A0,32) ISSUE(A1,33) ISSUE(A2,34) ISSUE(A3,35)                    \
    ISSUE(A4,36) ISSUE(A5,37) ISSUE(A6,38) ISSUE(A7,39)                    \
    WAIT8(8, B0,B1,B2,B3,B4,B5,B6,B7)                                      \
    R(24,B0) R(25,B1) R(26,B2) R(27,B3) R(28,B4) R(29,B5) R(30,B6) R(31,B7)\
    ISSUE(B0,40) ISSUE(B1,41) ISSUE(B2,42) ISSUE(B3,43)                    \
    ISSUE(B4,44) ISSUE(B5,45)                                              \
    WAIT8(6, A0,A1,A2,A3,A4,A5,A6,A7)                                      \
    R(32,A0) R(33,A1) R(34,A2) R(35,A3) R(36,A4) R(37,A5) R(38,A6) R(39,A7)\
    WAIT6(0, B0,B1,B2,B3,B4,B5)                                            \
    R(40,B0) R(41,B1) R(42,B2) R(43,B3) R(44,B4) R(45,B5)

#define ROW_FAST(J, V) FMAROW(J, V)
#define ROW_EDGE(J, V) FIX(J, V) FMAROW(J, V)

    if (tblk >= 1 && tblk <= 126) {
        LADDER(ROW_FAST)             // rows tb-15 .. tb+30 all in range
    } else {
        LADDER(ROW_EDGE)             // clamped addrs + zero-mult (2/128 tblks)
    }

#undef ROW_FAST
#undef ROW_EDGE
#undef LADDER
#undef ISSUE
#undef WAIT8
#undef WAIT6
#undef FIX
#undef FMAROW

    // nt dwordx2 stores; keep output out of L3 (R12)
    f32x2* op2 = (f32x2*)out + col2;
    #pragma unroll
    for (int i = 0; i < TP; ++i) {
        f32x2 r; r[0] = aA[i]; r[1] = aB[i];
        __builtin_nontemporal_store(r, &op2[(size_t)(tb + i) * NC2]);
    }
}

extern "C" void kernel_launch(void* const* d_in, const int* in_sizes, int n_in,
                              void* d_out, int out_size, void* d_ws, size_t ws_size,
                              hipStream_t stream) {
    const float* x      = (const float*)d_in[0];
    const float* weight = (const float*)d_in[1];
    const float* bias   = (const float*)d_in[2];
    float* out = (float*)d_out;
    // waves = heads(16) x batch-quads(8) x t-blocks(128) = 16384 -> 4096 blocks
    dim3 grid(H_DIM * 8 * (T_DIM / TP) / 4);
    dim3 block(256);
    lwconv_kernel<<<grid, block, 0, stream>>>(x, weight, bias, out);
}

// Round 19
// 50.770 us; speedup vs baseline: 9.4040x; 1.1061x over previous
//
#include <hip/hip_runtime.h>

// LightweightConv1d: x (T,B,C) f32, weight (H,1,K) f32 (softmax over K), bias (C) f32
// out[t,b,c] = bias[c] + sum_k softmax(w[h])[k] * x[t-P+k, b, c],  h = c / (C/H)
//
// FINAL (= R13, the series best at 50.4us): scalar streaming accumulators
// (TT=32, the allocator's <=64-live feasible corner), asm-opaque dword loads
// in double-buffered batches of 16 with counted s_waitcnt vmcnt(16) (never 0
// until drain), weights in SGPR via wave-per-head mapping, nt stores.
// Series conclusions: this op is pinned at the ~4.1-4.3 TB/s strided-pattern
// HBM wall (measured invariant across 10+ structures); bytes are at the
// feasible minimum (FETCH ~74MB, amp 1.94 at the TT=32 allocator corner);
// depth/width/bytes/occupancy/LDS levers all individually falsified.
#define T_DIM 2048
#define B_DIM 32
#define C_DIM 512
#define H_DIM 16
#define K_DIM 31
#define P_PAD 15
#define TT 32                      // outputs (accumulators) per thread
#define NCOL (B_DIM * C_DIM)       // 16384 floats between consecutive t
#define TSTEP 65536u               // NCOL*4 bytes: byte stride between t-rows

__global__ __launch_bounds__(256, 4)
void lwconv_kernel(const float* __restrict__ x, const float* __restrict__ weight,
                   const float* __restrict__ bias, float* __restrict__ out)
{
    const int wid  = __builtin_amdgcn_readfirstlane((int)(threadIdx.x >> 6));
    const int lane = threadIdx.x & 63;
    const int gw   = blockIdx.x * 4 + wid;        // global wave id (scalar)
    const int h    = gw & (H_DIM - 1);            // head (wave-uniform)
    const int bp   = (gw >> 4) & 15;              // batch pair (uniform)
    const int tblk = gw >> 8;                     // t-block 0..63 (uniform)
    const int c    = (h << 5) | (lane & 31);      // 32 channels of head h
    const int b    = (bp << 1) | (lane >> 5);     // 2 batches per wave
    const int col  = b * C_DIM + c;               // two 128B segments per wave

    // per-lane softmax of the head's 31 weights (uniform inputs), then -> SGPR
    float w[K_DIM];
    float m = -3.4e38f;
    #pragma unroll
    for (int k = 0; k < K_DIM; ++k) { w[k] = weight[h * K_DIM + k]; m = fmaxf(m, w[k]); }
    float s = 0.f;
    #pragma unroll
    for (int k = 0; k < K_DIM; ++k) { w[k] = __expf(w[k] - m); s += w[k]; }
    const float inv = 1.f / s;
    unsigned int ws[K_DIM];
    #pragma unroll
    for (int k = 0; k < K_DIM; ++k)
        ws[k] = __builtin_amdgcn_readfirstlane(__float_as_uint(w[k] * inv));

    const float bv = bias[c];
    const int tb = tblk * TT;                     // first output t of this thread
    float* op = out + col;

    float acc[TT];
    #pragma unroll
    for (int i = 0; i < TT; ++i) acc[i] = bv;

#define FMAS(J, V)                                                        \
    {                                                                     \
        const int ilo = ((J) - (K_DIM - 1)) > 0 ? ((J) - (K_DIM - 1)) : 0;\
        const int ihi = (J) < (TT - 1) ? (J) : (TT - 1);                  \
        _Pragma("unroll")                                                 \
        for (int i = ilo; i <= ihi; ++i)                                  \
            acc[i] = fmaf(__uint_as_float(ws[(J) - i]), (V), acc[i]);     \
    }

    if (tblk == 0 || tblk == (T_DIM / TT) - 1) {
        // boundary t-blocks (2 of 64): serial clamped path (R12-proven)
        const float* xp = x + col;
        #pragma unroll
        for (int j = 0; j < TT + K_DIM - 1; ++j) {
            const int t  = tb - P_PAD + j;
            int tc = t < 0 ? 0 : (t >= T_DIM ? T_DIM - 1 : t);
            float v = xp[(size_t)tc * NCOL];
            if (t < 0 || t >= T_DIM) v = 0.f;
            FMAS(j, v);
        }
    } else {
        // interior: rows tb-15 .. tb+48 all in-range (tblk 1..62); load 64 rows
        // (j=62,63 are dead: FMAS range empty) in 4 batches of 16, 2-deep dbuf.
        const unsigned long long xb = (unsigned long long)(const void*)x;
        unsigned int voff = ((unsigned)col << 2) + (unsigned)(tb - P_PAD) * TSTEP;
        float A[16], Bv[16];

#define ISSUE16(BUF)                                                      \
        _Pragma("unroll")                                                 \
        for (int u = 0; u < 16; ++u) {                                    \
            asm volatile("global_load_dword %0, %1, %2"                   \
                         : "=v"(BUF[u]) : "v"(voff), "s"(xb));            \
            voff += TSTEP;                                                \
        }

#define WAITB(N, BUF)                                                     \
        asm volatile("s_waitcnt vmcnt(" #N ")"                            \
                : "+v"(BUF[0]), "+v"(BUF[1]), "+v"(BUF[2]),  "+v"(BUF[3]),\
                  "+v"(BUF[4]), "+v"(BUF[5]), "+v"(BUF[6]),  "+v"(BUF[7]),\
                  "+v"(BUF[8]), "+v"(BUF[9]), "+v"(BUF[10]), "+v"(BUF[11]),\
                  "+v"(BUF[12]),"+v"(BUF[13]),"+v"(BUF[14]), "+v"(BUF[15]));

#define FMA16(BASE, BUF)                                                  \
        _Pragma("unroll")                                                 \
        for (int u = 0; u < 16; ++u) { FMAS((BASE) + u, BUF[u]); }

        ISSUE16(A);           // j 0-15   (16 in flight)
        ISSUE16(Bv);          // j 16-31  (32 in flight)
        WAITB(16, A);         // A landed; Bv still flying
        FMA16(0, A);
        ISSUE16(A);           // j 32-47  (32 in flight)
        WAITB(16, Bv);
        FMA16(16, Bv);
        ISSUE16(Bv);          // j 48-63  (32 in flight)
        WAITB(16, A);
        FMA16(32, A);
        WAITB(0, Bv);
        FMA16(48, Bv);        // j 62,63 produce no FMAs (empty range)

#undef ISSUE16
#undef WAITB
#undef FMA16
    }
#undef FMAS

    // nt stores: keep output lines out of L3 so the input stays resident (R12)
    #pragma unroll
    for (int i = 0; i < TT; ++i)
        __builtin_nontemporal_store(acc[i], &op[(size_t)(tb + i) * NCOL]);
}

extern "C" void kernel_launch(void* const* d_in, const int* in_sizes, int n_in,
                              void* d_out, int out_size, void* d_ws, size_t ws_size,
                              hipStream_t stream) {
    const float* x      = (const float*)d_in[0];
    const float* weight = (const float*)d_in[1];
    const float* bias   = (const float*)d_in[2];
    float* out = (float*)d_out;
    // waves = H(16) * batch-pairs(16) * t-blocks(64) = 16384 -> 4096 blocks of 4 waves
    dim3 grid(H_DIM * 16 * (T_DIM / TT) / 4);
    dim3 block(256);
    lwconv_kernel<<<grid, block, 0, stream>>>(x, weight, bias, out);
}